// Round 3
// baseline (731.030 us; speedup 1.0000x reference)
//
#include <hip/hip_runtime.h>
#include <hip/hip_bf16.h>
#include <math.h>

typedef __hip_bfloat16 bf16;

__device__ __forceinline__ float b2f(bf16 v) { return __bfloat162float(v); }

constexpr int B_ = 4, L_ = 2048, D_IN_ = 80, D_ = 128, H_ = 16, WIN_ = 64, DH_ = 8;
constexpr int T_ = B_ * L_;          // 8192 tokens

// Intermediates in static device globals (no ws_size dependence).
__device__ float g_h  [T_ * D_];
__device__ float g_qkv[T_ * 3 * D_];
__device__ float g_ctx[T_ * D_];
__device__ float g_ao [T_ * D_];
__device__ float g_f1 [T_ * D_];
__device__ float g_f2 [T_ * D_];
__device__ int   g_isbf;             // 1 = buffers are bf16, 0 = fp32

// Load element i of an input buffer whose storage dtype is decided at runtime.
template <bool BF>
__device__ __forceinline__ float ldin(const void* p, size_t i) {
    if (BF) return b2f(((const bf16*)p)[i]);
    else    return ((const float*)p)[i];
}

// ---------------------------------------------------------------------------
// Dtype detector: bn_rv ~ U[0.5,1.5]. If stored bf16, low 16 bits of each
// 32-bit word are a bf16 value in [0.5,1.5]; if fp32, they're random mantissa
// bits (in-range prob ~0.6%). 32 words = 128 B, safe under either layout.
// ---------------------------------------------------------------------------
__global__ void detect_kernel(const void* __restrict__ bn_rv) {
    if (blockIdx.x == 0 && threadIdx.x == 0) {
        const unsigned* w = (const unsigned*)bn_rv;
        int cnt = 0;
        for (int i = 0; i < 32; i++) {
            float v = __uint_as_float((w[i] & 0xFFFFu) << 16);  // low half as bf16
            if (v > 0.4f && v < 1.6f) cnt++;
        }
        g_isbf = (cnt >= 16) ? 1 : 0;
    }
}

// ---------------------------------------------------------------------------
// conv1x1 + ReLU + BN(eval) + sinusoidal posenc -> g_h.  One block per token.
// ---------------------------------------------------------------------------
template <bool BF>
__device__ __forceinline__ void pre_body(const void* x, const void* conv_w,
                                         const void* conv_b, const void* bn_g,
                                         const void* bn_b, const void* bn_rm,
                                         const void* bn_rv) {
    int t = blockIdx.x;
    int tid = threadIdx.x;
    int l = t & (L_ - 1);

    __shared__ float xs[D_IN_];
    if (tid < D_IN_) xs[tid] = ldin<BF>(x, (size_t)t * D_IN_ + tid);
    __syncthreads();

    int o = tid;
    float acc = ldin<BF>(conv_b, o);
#pragma unroll 8
    for (int i = 0; i < D_IN_; i++)
        acc = fmaf(xs[i], ldin<BF>(conv_w, (size_t)o * D_IN_ + i), acc);
    acc = fmaxf(acc, 0.0f);
    float g  = ldin<BF>(bn_g, o),  bb = ldin<BF>(bn_b, o);
    float rm = ldin<BF>(bn_rm, o), rv = ldin<BF>(bn_rv, o);
    acc = (acc - rm) * (g * rsqrtf(rv + 1e-5f)) + bb;

    int j = o >> 1;
    double ang = (double)l * exp((double)j * (-9.210340371976184 / 128.0));
    float p = (o & 1) ? (float)cos(ang) : (float)sin(ang);

    g_h[(size_t)t * D_ + o] = acc + p;
}

__global__ void pre_kernel(const void* x, const void* conv_w, const void* conv_b,
                           const void* bn_g, const void* bn_b,
                           const void* bn_rm, const void* bn_rv) {
    if (g_isbf) pre_body<true >(x, conv_w, conv_b, bn_g, bn_b, bn_rm, bn_rv);
    else        pre_body<false>(x, conv_w, conv_b, bn_g, bn_b, bn_rm, bn_rv);
}

// ---------------------------------------------------------------------------
// GEMM: Y[t,o] = act( sum_d X[t,d]*W[o,d] + bias[o] ).  Block = token.
// ---------------------------------------------------------------------------
template <int K, int N, bool RELU, bool BF>
__device__ __forceinline__ void gemm_body(const float* __restrict__ X,
                                          const void* __restrict__ W,
                                          const void* __restrict__ bias,
                                          float* __restrict__ Y) {
    int t = blockIdx.x;
    int o = blockIdx.y * 128 + threadIdx.x;

    __shared__ float xs[K];
    for (int d = threadIdx.x; d < K; d += 128) xs[d] = X[(size_t)t * K + d];
    __syncthreads();

    if (o >= N) return;
    float acc = ldin<BF>(bias, o);
#pragma unroll 8
    for (int d = 0; d < K; d++)
        acc = fmaf(xs[d], ldin<BF>(W, (size_t)o * K + d), acc);
    if (RELU) acc = fmaxf(acc, 0.0f);
    Y[(size_t)t * N + o] = acc;
}

__global__ void k_qkv(const void* W, const void* b) {
    if (g_isbf) gemm_body<128, 384, false, true >(g_h, W, b, g_qkv);
    else        gemm_body<128, 384, false, false>(g_h, W, b, g_qkv);
}
__global__ void k_outproj(const void* W, const void* b) {
    if (g_isbf) gemm_body<128, 128, false, true >(g_ctx, W, b, g_ao);
    else        gemm_body<128, 128, false, false>(g_ctx, W, b, g_ao);
}
__global__ void k_ff1(const void* W, const void* b) {
    if (g_isbf) gemm_body<128, 128, true, true >(g_ao, W, b, g_f1);
    else        gemm_body<128, 128, true, false>(g_ao, W, b, g_f1);
}
__global__ void k_ff2(const void* W, const void* b) {
    if (g_isbf) gemm_body<128, 128, false, true >(g_f1, W, b, g_f2);
    else        gemm_body<128, 128, false, false>(g_f1, W, b, g_f2);
}

// final head: K=128, N=80, output dtype follows the detected input dtype
template <bool BF>
__device__ __forceinline__ void fc_body(const void* W, const void* bias, void* out) {
    int t = blockIdx.x;
    int o = threadIdx.x;

    __shared__ float xs[128];
    xs[threadIdx.x] = g_f2[(size_t)t * 128 + threadIdx.x];
    __syncthreads();

    if (o >= 80) return;
    float acc = ldin<BF>(bias, o);
#pragma unroll 8
    for (int d = 0; d < 128; d++)
        acc = fmaf(xs[d], ldin<BF>(W, (size_t)o * 128 + d), acc);
    if (BF) ((bf16*)out)[(size_t)t * 80 + o] = __float2bfloat16(acc);
    else    ((float*)out)[(size_t)t * 80 + o] = acc;
}

__global__ void k_fc(const void* W, const void* bias, void* out) {
    if (g_isbf) fc_body<true >(W, bias, out);
    else        fc_body<false>(W, bias, out);
}

// ---------------------------------------------------------------------------
// Local-window attention: one thread per (b,h,q); |q-j| in [1,64]; dh=8.
// ---------------------------------------------------------------------------
__global__ void attn_kernel() {
    int gid = blockIdx.x * blockDim.x + threadIdx.x;
    int q = gid & (L_ - 1);
    int bh = gid >> 11;
    int hh = bh & (H_ - 1);
    int b = bh >> 4;

    const float scale = 0.35355339059327373f;          // 1/sqrt(8)

    float qv[DH_];
    size_t qbase = ((size_t)(b * L_ + q)) * (3 * D_) + hh * DH_;
#pragma unroll
    for (int d = 0; d < DH_; d++) qv[d] = g_qkv[qbase + d];

    float m = -1e30f, lsum = 0.0f;
    float acc[DH_];
#pragma unroll
    for (int d = 0; d < DH_; d++) acc[d] = 0.0f;

    int jlo = q - WIN_; if (jlo < 0) jlo = 0;
    int jhi = q + WIN_; if (jhi > L_ - 1) jhi = L_ - 1;

    for (int j = jlo; j <= jhi; j++) {
        if (j == q) continue;
        size_t kb = ((size_t)(b * L_ + j)) * (3 * D_) + D_ + hh * DH_;
        float s = 0.0f;
#pragma unroll
        for (int d = 0; d < DH_; d++) s = fmaf(qv[d], g_qkv[kb + d], s);
        s *= scale;
        float mn = fmaxf(m, s);
        float corr = expf(m - mn);
        float w = expf(s - mn);
        lsum = lsum * corr + w;
        size_t vb = kb + D_;
#pragma unroll
        for (int d = 0; d < DH_; d++) acc[d] = fmaf(w, g_qkv[vb + d], acc[d] * corr);
        m = mn;
    }

    float inv = 1.0f / lsum;
    size_t cb = ((size_t)(b * L_ + q)) * D_ + hh * DH_;
#pragma unroll
    for (int d = 0; d < DH_; d++) g_ctx[cb + d] = acc[d] * inv;
}

// ---------------------------------------------------------------------------
extern "C" void kernel_launch(void* const* d_in, const int* in_sizes, int n_in,
                              void* d_out, int out_size, void* d_ws, size_t ws_size,
                              hipStream_t stream) {
    const void* x         = d_in[0];
    const void* conv_w    = d_in[1];
    const void* conv_b    = d_in[2];
    const void* bn_g      = d_in[3];
    const void* bn_b      = d_in[4];
    const void* bn_rm     = d_in[5];
    const void* bn_rv     = d_in[6];
    const void* in_proj_w = d_in[7];
    const void* in_proj_b = d_in[8];
    const void* out_w     = d_in[9];
    const void* out_b     = d_in[10];
    const void* ff_w1     = d_in[11];
    const void* ff_b1     = d_in[12];
    const void* ff_w2     = d_in[13];
    const void* ff_b2     = d_in[14];
    const void* fc_w      = d_in[15];
    const void* fc_b      = d_in[16];

    detect_kernel<<<1, 64, 0, stream>>>(bn_rv);

    pre_kernel<<<T_, 128, 0, stream>>>(x, conv_w, conv_b, bn_g, bn_b, bn_rm, bn_rv);

    k_qkv<<<dim3(T_, 3), 128, 0, stream>>>(in_proj_w, in_proj_b);

    attn_kernel<<<(B_ * H_ * L_) / 256, 256, 0, stream>>>();

    k_outproj<<<dim3(T_, 1), 128, 0, stream>>>(out_w, out_b);
    k_ff1<<<dim3(T_, 1), 128, 0, stream>>>(ff_w1, ff_b1);
    k_ff2<<<dim3(T_, 1), 128, 0, stream>>>(ff_w2, ff_b2);
    k_fc<<<dim3(T_, 1), 128, 0, stream>>>(fc_w, fc_b, d_out);
}

// Round 4
// 261.252 us; speedup vs baseline: 2.7982x; 2.7982x over previous
//
#include <hip/hip_runtime.h>
#include <hip/hip_bf16.h>
#include <math.h>

constexpr int B_ = 4, L_ = 2048, DIN = 80, D_ = 128, H_ = 16, DH = 8;
constexpr int T_ = B_ * L_;      // 8192 tokens
constexpr int LDX = T_;          // col-major activations: act[chan][token]

// ---- static device globals (d_ws unused; confirmed safe in round 3) ----
__device__ float g_xT  [DIN * T_];        // x transposed [80][8192]
__device__ float g_posT[D_ * L_];         // posenc [128][2048]
__device__ float g_h   [D_ * T_];         // conv+bn+pos out, col-major
__device__ float g_ctx [D_ * T_];
__device__ float g_ao  [D_ * T_];
__device__ float g_f1  [D_ * T_];
__device__ float g_f2  [D_ * T_];
__device__ float g_q3  [B_ * H_ * L_ * DH];   // head-major [b][h][t][8]
__device__ float g_k3  [B_ * H_ * L_ * DH];
__device__ float g_v3  [B_ * H_ * L_ * DH];
__device__ float g_WconvT[DIN * D_];      // [k][o]
__device__ float g_WqkvT [D_ * 3 * D_];   // [128][384]
__device__ float g_WoutT [D_ * D_];
__device__ float g_Wff1T [D_ * D_];
__device__ float g_Wff2T [D_ * D_];
__device__ float g_WfcT  [D_ * D_];       // zero-padded cols 80..127
__device__ float g_bfc   [D_];            // zero-padded fc bias

template <int ID> __device__ __forceinline__ float* actp() {
    if (ID == 0) return g_xT;
    if (ID == 1) return g_h;
    if (ID == 2) return g_ctx;
    if (ID == 3) return g_ao;
    if (ID == 4) return g_f1;
    return g_f2;
}
template <int ID> __device__ __forceinline__ const float* wtp() {
    if (ID == 0) return g_WconvT;
    if (ID == 1) return g_WqkvT;
    if (ID == 2) return g_WoutT;
    if (ID == 3) return g_Wff1T;
    if (ID == 4) return g_Wff2T;
    return g_WfcT;
}

// ---------------------------------------------------------------------------
// prep: posenc (fp64, faithful to ref) + transpose x and all weights.
// One thread per element; region if-chain. 911488 threads.
// ---------------------------------------------------------------------------
__global__ void prep_kernel(const float* __restrict__ x,
                            const float* __restrict__ conv_w,
                            const float* __restrict__ in_proj_w,
                            const float* __restrict__ out_w,
                            const float* __restrict__ ff_w1,
                            const float* __restrict__ ff_w2,
                            const float* __restrict__ fc_w,
                            const float* __restrict__ fc_b) {
    int idx = blockIdx.x * 256 + threadIdx.x;
    if (idx < 131072) {                       // posenc: l in [0,2048), j in [0,64)
        int l = idx >> 6, j = idx & 63;
        double ang = (double)l * exp((double)j * (-9.210340371976184 / 128.0));
        g_posT[(2 * j) * L_ + l]     = (float)sin(ang);
        g_posT[(2 * j + 1) * L_ + l] = (float)cos(ang);
        return;
    }
    idx -= 131072;
    if (idx < DIN * T_) {                     // xT
        int t = idx / DIN, k = idx - t * DIN;
        g_xT[k * T_ + t] = x[idx];
        return;
    }
    idx -= DIN * T_;
    if (idx < D_ * DIN) {                     // conv_w [128][80] -> [80][128]
        int o = idx / DIN, k = idx - o * DIN;
        g_WconvT[k * D_ + o] = conv_w[idx];
        return;
    }
    idx -= D_ * DIN;
    if (idx < 3 * D_ * D_) {                  // in_proj_w [384][128] -> [128][384]
        int o = idx >> 7, k = idx & 127;
        g_WqkvT[k * (3 * D_) + o] = in_proj_w[idx];
        return;
    }
    idx -= 3 * D_ * D_;
    if (idx < D_ * D_) { int o = idx >> 7, k = idx & 127; g_WoutT[k * D_ + o] = out_w[idx]; return; }
    idx -= D_ * D_;
    if (idx < D_ * D_) { int o = idx >> 7, k = idx & 127; g_Wff1T[k * D_ + o] = ff_w1[idx]; return; }
    idx -= D_ * D_;
    if (idx < D_ * D_) { int o = idx >> 7, k = idx & 127; g_Wff2T[k * D_ + o] = ff_w2[idx]; return; }
    idx -= D_ * D_;
    if (idx < D_ * D_) {                      // fc_w [80][128] -> padded [128][128]
        int k = idx >> 7, o = idx & 127;
        g_WfcT[k * D_ + o] = (o < 80) ? fc_w[o * D_ + k] : 0.0f;
        return;
    }
    idx -= D_ * D_;
    if (idx < D_) { g_bfc[idx] = (idx < 80) ? fc_b[idx] : 0.0f; return; }
}

// ---------------------------------------------------------------------------
// Tiled fp32 GEMM: Y[c][t] = epi( sum_k X[k][t] * Wt[k][c] + bias[c] )
// BM=16 tokens x BN=128 cols per block, 128 threads, 4x4 per thread, BK chunks.
// EPI: 0 none, 1 relu, 2 conv(relu+bn+pos), 3 qkv scatter, 4 fc row-major store
// ---------------------------------------------------------------------------
template <int K, int BK, int LDW, int EPI, int XID, int WID, int YID>
__global__ __launch_bounds__(128) void gemm_kernel(
        const float* __restrict__ bias,
        const float* __restrict__ bg, const float* __restrict__ bb,
        const float* __restrict__ brm, const float* __restrict__ brv,
        float* __restrict__ outp) {
    __shared__ float Xs[BK][16];
    __shared__ float Ws[BK][128];
    const float* X  = actp<XID>();
    const float* Wt = wtp<WID>();
    int tid = threadIdx.x;
    int t0 = blockIdx.x * 16;
    int cb = blockIdx.y * 128;               // col base (qkv slabs)
    int tc = tid & 31, tr = tid >> 5;        // col group [0,32), row group [0,4)
    float acc[4][4] = {};

    for (int kc = 0; kc < K; kc += BK) {
        if (tid < BK * 4) {                  // stage X chunk [BK][16]
            int kk = tid >> 2, f = tid & 3;
            *(float4*)&Xs[kk][f * 4] =
                *(const float4*)&X[(size_t)(kc + kk) * LDX + t0 + f * 4];
        }
        {                                    // stage W chunk [BK][128]
            int c4 = tid & 31, kk0 = tid >> 5;
#pragma unroll
            for (int kk = kk0; kk < BK; kk += 4)
                *(float4*)&Ws[kk][c4 * 4] =
                    *(const float4*)&Wt[(size_t)(kc + kk) * LDW + cb + c4 * 4];
        }
        __syncthreads();
#pragma unroll 8
        for (int kk = 0; kk < BK; ++kk) {
            float4 a = *(float4*)&Xs[kk][tr * 4];
            float4 w = *(float4*)&Ws[kk][tc * 4];
            float av[4] = {a.x, a.y, a.z, a.w};
            float wv[4] = {w.x, w.y, w.z, w.w};
#pragma unroll
            for (int i = 0; i < 4; i++)
#pragma unroll
                for (int jj = 0; jj < 4; jj++)
                    acc[i][jj] = fmaf(av[i], wv[jj], acc[i][jj]);
        }
        __syncthreads();
    }

    int c0 = tc * 4;
    if (EPI == 3) {                          // qkv scatter to head-major
        float* dst = (blockIdx.y == 0) ? g_q3 : (blockIdx.y == 1 ? g_k3 : g_v3);
#pragma unroll
        for (int i = 0; i < 4; i++) {
            int t = t0 + tr * 4 + i;
            int b = t >> 11, l = t & 2047;
#pragma unroll
            for (int jj = 0; jj < 4; jj++) {
                int c = c0 + jj;
                float v = acc[i][jj] + bias[cb + c];
                int h = c >> 3, d = c & 7;
                dst[(((size_t)(b * H_ + h)) * L_ + l) * DH + d] = v;
            }
        }
        return;
    }
    if (EPI == 4) {                          // fc: row-major [t][80]
#pragma unroll
        for (int i = 0; i < 4; i++) {
            int t = t0 + tr * 4 + i;
#pragma unroll
            for (int jj = 0; jj < 4; jj++) {
                int c = c0 + jj;
                if (c < 80) outp[(size_t)t * 80 + c] = acc[i][jj] + g_bfc[c];
            }
        }
        return;
    }
    float* Y = actp<YID>();
#pragma unroll
    for (int jj = 0; jj < 4; jj++) {
        int c = c0 + jj;
        float bv = bias[c];
        float vs[4];
#pragma unroll
        for (int i = 0; i < 4; i++) {
            float v = acc[i][jj] + bv;
            if (EPI == 1) v = fmaxf(v, 0.0f);
            if (EPI == 2) {
                v = fmaxf(v, 0.0f);
                v = (v - brm[c]) * (bg[c] * rsqrtf(brv[c] + 1e-5f)) + bb[c];
                v += g_posT[c * L_ + ((t0 + tr * 4 + i) & 2047)];
            }
            vs[i] = v;
        }
        *(float4*)&Y[(size_t)c * LDX + t0 + tr * 4] = *(float4*)vs;
    }
}

// ---------------------------------------------------------------------------
// Attention: one thread handles q0=2p, q1=2p+1 (shared K/V loads).
// Window |q-j| in [1,64]; no max-subtraction (scores bounded, exp safe).
// ---------------------------------------------------------------------------
__global__ __launch_bounds__(256) void attn_kernel() {
    int gid = blockIdx.x * 256 + threadIdx.x;      // [0, 65536)
    int bh = gid >> 10, pq = gid & 1023;
    int q0 = pq * 2, q1 = q0 + 1;
    const float* qb = g_q3 + (size_t)bh * L_ * DH;
    const float* kb = g_k3 + (size_t)bh * L_ * DH;
    const float* vb = g_v3 + (size_t)bh * L_ * DH;
    const float sc = 0.35355339059327373f;         // 1/sqrt(8)

    float qa[8], qc[8];
#pragma unroll
    for (int d = 0; d < 8; d++) {
        qa[d] = qb[q0 * 8 + d] * sc;
        qc[d] = qb[q1 * 8 + d] * sc;
    }
    int jlo = q0 - 64; if (jlo < 0) jlo = 0;
    int jhi = q1 + 64; if (jhi > L_ - 1) jhi = L_ - 1;

    float l0 = 0.f, l1 = 0.f;
    float A0[8] = {}, A1[8] = {};
#pragma unroll 2
    for (int j = jlo; j <= jhi; j++) {
        float kv[8], vv[8];
        *(float4*)kv       = *(const float4*)&kb[j * 8];
        *(float4*)(kv + 4) = *(const float4*)&kb[j * 8 + 4];
        *(float4*)vv       = *(const float4*)&vb[j * 8];
        *(float4*)(vv + 4) = *(const float4*)&vb[j * 8 + 4];
        float s0 = 0.f, s1 = 0.f;
#pragma unroll
        for (int d = 0; d < 8; d++) {
            s0 = fmaf(qa[d], kv[d], s0);
            s1 = fmaf(qc[d], kv[d], s1);
        }
        bool ok0 = (j != q0) && (j <= q0 + 64);
        bool ok1 = (j != q1) && (j >= q1 - 64);
        float w0 = ok0 ? expf(s0) : 0.f;
        float w1 = ok1 ? expf(s1) : 0.f;
        l0 += w0; l1 += w1;
#pragma unroll
        for (int d = 0; d < 8; d++) {
            A0[d] = fmaf(w0, vv[d], A0[d]);
            A1[d] = fmaf(w1, vv[d], A1[d]);
        }
    }
    float i0 = 1.f / l0, i1 = 1.f / l1;
    int b = bh >> 4, h = bh & 15;
    int tb = b * L_;
#pragma unroll
    for (int d = 0; d < 8; d++) {              // col-major ctx [c][t]
        g_ctx[(size_t)(h * 8 + d) * LDX + tb + q0] = A0[d] * i0;
        g_ctx[(size_t)(h * 8 + d) * LDX + tb + q1] = A1[d] * i1;
    }
}

// ---------------------------------------------------------------------------
extern "C" void kernel_launch(void* const* d_in, const int* in_sizes, int n_in,
                              void* d_out, int out_size, void* d_ws, size_t ws_size,
                              hipStream_t stream) {
    const float* x         = (const float*)d_in[0];
    const float* conv_w    = (const float*)d_in[1];
    const float* conv_b    = (const float*)d_in[2];
    const float* bn_g      = (const float*)d_in[3];
    const float* bn_b      = (const float*)d_in[4];
    const float* bn_rm     = (const float*)d_in[5];
    const float* bn_rv     = (const float*)d_in[6];
    const float* in_proj_w = (const float*)d_in[7];
    const float* in_proj_b = (const float*)d_in[8];
    const float* out_w     = (const float*)d_in[9];
    const float* out_b     = (const float*)d_in[10];
    const float* ff_w1     = (const float*)d_in[11];
    const float* ff_b1     = (const float*)d_in[12];
    const float* ff_w2     = (const float*)d_in[13];
    const float* ff_b2     = (const float*)d_in[14];
    const float* fc_w      = (const float*)d_in[15];
    const float* fc_b      = (const float*)d_in[16];

    prep_kernel<<<3561, 256, 0, stream>>>(x, conv_w, in_proj_w, out_w,
                                          ff_w1, ff_w2, fc_w, fc_b);

    // conv+relu+bn+posenc: K=80, 5 chunks of 16
    gemm_kernel<80, 16, 128, 2, 0, 0, 1><<<dim3(512, 1), 128, 0, stream>>>(
        conv_b, bn_g, bn_b, bn_rm, bn_rv, nullptr);

    // qkv: K=128, 3 slabs of 128 cols, scatter to head-major
    gemm_kernel<128, 32, 384, 3, 1, 1, 0><<<dim3(512, 3), 128, 0, stream>>>(
        in_proj_b, nullptr, nullptr, nullptr, nullptr, nullptr);

    attn_kernel<<<256, 256, 0, stream>>>();

    gemm_kernel<128, 32, 128, 0, 2, 2, 3><<<dim3(512, 1), 128, 0, stream>>>(
        out_b, nullptr, nullptr, nullptr, nullptr, nullptr);
    gemm_kernel<128, 32, 128, 1, 3, 3, 4><<<dim3(512, 1), 128, 0, stream>>>(
        ff_b1, nullptr, nullptr, nullptr, nullptr, nullptr);
    gemm_kernel<128, 32, 128, 0, 4, 4, 5><<<dim3(512, 1), 128, 0, stream>>>(
        ff_b2, nullptr, nullptr, nullptr, nullptr, nullptr);
    gemm_kernel<128, 32, 128, 4, 5, 5, 0><<<dim3(512, 1), 128, 0, stream>>>(
        nullptr, nullptr, nullptr, nullptr, nullptr, (float*)d_out);
}

// Round 5
// 175.507 us; speedup vs baseline: 4.1652x; 1.4886x over previous
//
#include <hip/hip_runtime.h>
#include <hip/hip_bf16.h>
#include <math.h>

constexpr int B_ = 4, L_ = 2048, DIN = 80, D_ = 128, H_ = 16, DH = 8;
constexpr int T_ = B_ * L_;
constexpr int LDX = T_;              // col-major activations act[chan][token]

// ---- static device globals ----
__device__ float g_xT  [DIN * T_];          // [80][8192]
__device__ float g_posT[D_ * L_];           // [128][2048]
__device__ float g_h   [D_ * T_];
__device__ float g_ctx [D_ * T_];
__device__ float g_f1  [D_ * T_];
__device__ float g_q3  [B_ * H_ * L_ * DH]; // [b][h][l][8]
__device__ float g_k3  [B_ * H_ * L_ * DH];
__device__ float g_v3  [B_ * H_ * L_ * DH];
__device__ float g_WconvT[DIN * D_];        // [k][o]
__device__ float g_WqkvT [D_ * 3 * D_];     // [128][384]
__device__ float g_Wf1T  [D_ * D_];         // fused (W1·Wo)^T  [d][f]
__device__ float g_WfcT  [D_ * D_];         // fused (Wfc·W2)^T [f][o], o>=80 zero
__device__ float g_bf1   [D_];              // W1·bo + b1
__device__ float g_bfc   [D_];              // Wfc·b2 + bfc, padded 0

// ---------------------------------------------------------------------------
// prep_fold: posenc + transposes + the two weight-fold GEMMs, one dispatch.
// blocks [0,512) posenc | [512,3072) xT | [3072,3112) WconvT |
// [3112,3304) WqkvT | [3304,3368) fold1 | [3368,3432) fold2
// ---------------------------------------------------------------------------
__global__ void prep_fold(const float* __restrict__ x,
                          const float* __restrict__ conv_w,
                          const float* __restrict__ in_proj_w,
                          const float* __restrict__ out_w,
                          const float* __restrict__ out_b,
                          const float* __restrict__ ff_w1,
                          const float* __restrict__ ff_b1,
                          const float* __restrict__ ff_w2,
                          const float* __restrict__ ff_b2,
                          const float* __restrict__ fc_w,
                          const float* __restrict__ fc_b) {
    __shared__ float rowbuf[2][128];
    __shared__ float red[256];
    int bid = blockIdx.x, tid = threadIdx.x;

    if (bid < 512) {                           // posenc
        int idx = bid * 256 + tid;             // [0, 131072)
        int l = idx >> 6, j = idx & 63;
        double ang = (double)l * exp((double)j * (-9.210340371976184 / 128.0));
        g_posT[(2 * j) * L_ + l]     = (float)sin(ang);
        g_posT[(2 * j + 1) * L_ + l] = (float)cos(ang);
        return;
    }
    if (bid < 3072) {                          // x transpose
        int e = (bid - 512) * 256 + tid;       // [0, 655360)
        int t = e / 80, k = e - t * 80;
        g_xT[k * T_ + t] = x[e];
        return;
    }
    if (bid < 3112) {                          // conv_w [128][80] -> [80][128]
        int e = (bid - 3072) * 256 + tid;      // [0, 10240)
        int o = e / 80, k = e - o * 80;
        g_WconvT[k * D_ + o] = conv_w[e];
        return;
    }
    if (bid < 3304) {                          // in_proj_w [384][128] -> [128][384]
        int e = (bid - 3112) * 256 + tid;      // [0, 49152)
        int o = e >> 7, k = e & 127;
        g_WqkvT[k * (3 * D_) + o] = in_proj_w[e];
        return;
    }
    if (bid < 3368) {                          // fold1: M1=W1·Wo, b1'=W1·bo+b1
        int sub = tid >> 7, k = tid & 127;
        int f = (bid - 3304) * 2 + sub;
        rowbuf[sub][k] = ff_w1[f * 128 + k];
        __syncthreads();
        float acc = 0.f;
#pragma unroll 8
        for (int o = 0; o < 128; o++)
            acc = fmaf(rowbuf[sub][o], out_w[o * 128 + k], acc);
        g_Wf1T[k * 128 + f] = acc;
        red[tid] = rowbuf[sub][k] * out_b[k];
        __syncthreads();
        for (int s = 64; s > 0; s >>= 1) {
            if (k < s) red[tid] += red[tid + s];
            __syncthreads();
        }
        if (k == 0) g_bf1[f] = red[sub * 128] + ff_b1[f];
        return;
    }
    {                                          // fold2: M2=Wfc·W2, b2'=Wfc·b2+bfc
        int sub = tid >> 7, k = tid & 127;
        int o = (bid - 3368) * 2 + sub;
        rowbuf[sub][k] = (o < 80) ? fc_w[o * 128 + k] : 0.f;
        __syncthreads();
        float acc = 0.f;
#pragma unroll 8
        for (int d = 0; d < 128; d++)
            acc = fmaf(rowbuf[sub][d], ff_w2[d * 128 + k], acc);
        g_WfcT[k * 128 + o] = acc;
        red[tid] = rowbuf[sub][k] * ff_b2[k];
        __syncthreads();
        for (int s = 64; s > 0; s >>= 1) {
            if (k < s) red[tid] += red[tid + s];
            __syncthreads();
        }
        if (k == 0) g_bfc[o] = (o < 80) ? (red[sub * 128] + fc_b[o]) : 0.f;
        return;
    }
}

// ---------------------------------------------------------------------------
// GEMM: BM=64 tokens x BN=64 cols, 256 threads, 4x4/thread, full-K in LDS,
// single barrier. Y[c][t] = epi( sum_k X[k][t]*Wt[k][c] + bias[c] )
// EPI: 1 relu col-major, 2 conv(relu+bn+pos), 3 qkv scatter, 4 fc row-major
// ---------------------------------------------------------------------------
template <int K, int LDW, int EPI>
__global__ __launch_bounds__(256) void gemm_kernel(
        const float* __restrict__ X, const float* __restrict__ Wt,
        const float* __restrict__ bias,
        const float* __restrict__ bg, const float* __restrict__ bb,
        const float* __restrict__ brm, const float* __restrict__ brv,
        float* __restrict__ Y) {
    __shared__ float Xs[K][64];
    __shared__ float Ws[K][64];
    int tid = threadIdx.x;
    int t0 = blockIdx.x * 64;
    int cb = blockIdx.y * 64;
    int tc = tid & 15, tr = tid >> 4;          // 16 col-groups, 16 token-groups

    for (int i = tid; i < K * 16; i += 256) {  // stage X tile
        int k = i >> 4, f = i & 15;
        *(float4*)&Xs[k][f * 4] = *(const float4*)&X[(size_t)k * LDX + t0 + f * 4];
    }
    for (int i = tid; i < K * 16; i += 256) {  // stage W tile
        int k = i >> 4, f = i & 15;
        *(float4*)&Ws[k][f * 4] = *(const float4*)&Wt[(size_t)k * LDW + cb + f * 4];
    }
    __syncthreads();

    float acc[4][4] = {};
#pragma unroll 4
    for (int k = 0; k < K; ++k) {
        float4 a = *(float4*)&Xs[k][tr * 4];
        float4 w = *(float4*)&Ws[k][tc * 4];
        float av[4] = {a.x, a.y, a.z, a.w};
        float wv[4] = {w.x, w.y, w.z, w.w};
#pragma unroll
        for (int i = 0; i < 4; i++)
#pragma unroll
            for (int jj = 0; jj < 4; jj++)
                acc[i][jj] = fmaf(av[i], wv[jj], acc[i][jj]);
    }

    if (EPI == 3) {                            // qkv scatter to head-major
#pragma unroll
        for (int i = 0; i < 4; i++) {
            int t = t0 + tr * 4 + i;
            int b = t >> 11, l = t & 2047;
#pragma unroll
            for (int jj = 0; jj < 4; jj++) {
                int C = cb + tc * 4 + jj;      // [0,384)
                float v = acc[i][jj] + bias[C];
                int slab = C >> 7, cs = C & 127;
                float* dst = (slab == 0) ? g_q3 : (slab == 1 ? g_k3 : g_v3);
                dst[(((size_t)(b * H_ + (cs >> 3))) * L_ + l) * DH + (cs & 7)] = v;
            }
        }
        return;
    }
    if (EPI == 4) {                            // fc row-major [t][80]
#pragma unroll
        for (int i = 0; i < 4; i++) {
            int t = t0 + tr * 4 + i;
            int c0 = cb + tc * 4;
            if (c0 < 80) {
                float vs[4];
#pragma unroll
                for (int jj = 0; jj < 4; jj++) vs[jj] = acc[i][jj] + bias[c0 + jj];
                *(float4*)&Y[(size_t)t * 80 + c0] = *(float4*)vs;
            }
        }
        return;
    }
#pragma unroll
    for (int jj = 0; jj < 4; jj++) {
        int c = cb + tc * 4 + jj;
        float bv = bias[c];
        float vs[4];
#pragma unroll
        for (int i = 0; i < 4; i++) {
            float v = acc[i][jj] + bv;
            if (EPI == 1) v = fmaxf(v, 0.0f);
            if (EPI == 2) {
                v = fmaxf(v, 0.0f);
                v = (v - brm[c]) * (bg[c] * rsqrtf(brv[c] + 1e-5f)) + bb[c];
                v += g_posT[c * L_ + ((t0 + tr * 4) & 2047) + i];
            }
            vs[i] = v;
        }
        *(float4*)&Y[(size_t)c * LDX + t0 + tr * 4] = *(float4*)vs;
    }
}

// ---------------------------------------------------------------------------
// Attention, LDS-staged. Block = (bh, 256-query tile), 128 threads, 2 q each.
// Stage K/V window [qb-64, qb+319] (385 slots, zero-filled OOB) coalesced.
// ---------------------------------------------------------------------------
__global__ __launch_bounds__(128) void attn_kernel() {
    __shared__ float Ks[385 * 8];
    __shared__ float Vs[385 * 8];
    int bh = blockIdx.x;
    int qb = blockIdx.y * 256;
    int tid = threadIdx.x;
    int kbase = qb - 64;

    const float* kgl = g_k3 + (size_t)bh * L_ * DH;
    const float* vgl = g_v3 + (size_t)bh * L_ * DH;
    const float* qgl = g_q3 + (size_t)bh * L_ * DH;

    for (int i = tid; i < 385 * 2; i += 128) {  // stage (f4 granules)
        int li = i >> 1, half = i & 1;
        int j = kbase + li;
        float4 kf = {0, 0, 0, 0}, vf = {0, 0, 0, 0};
        if (j >= 0 && j < L_) {
            kf = *(const float4*)&kgl[j * 8 + half * 4];
            vf = *(const float4*)&vgl[j * 8 + half * 4];
        }
        *(float4*)&Ks[li * 8 + half * 4] = kf;
        *(float4*)&Vs[li * 8 + half * 4] = vf;
    }
    __syncthreads();

    const float sc = 0.35355339059327373f;      // 1/sqrt(8)
    int q0 = qb + 2 * tid;
    float qa[8], qc[8];
#pragma unroll
    for (int d = 0; d < 8; d++) {
        qa[d] = qgl[q0 * 8 + d] * sc;
        qc[d] = qgl[(q0 + 1) * 8 + d] * sc;
    }

    float l0 = 0.f, l1 = 0.f;
    float A0[8] = {}, A1[8] = {};
    int li0 = 2 * tid;                          // local index of j = q0-64
#pragma unroll 2
    for (int it = 0; it < 130; it++) {
        int li = li0 + it;
        int j = kbase + li;
        float kv[8], vv[8];
        *(float4*)kv       = *(float4*)&Ks[li * 8];
        *(float4*)(kv + 4) = *(float4*)&Ks[li * 8 + 4];
        *(float4*)vv       = *(float4*)&Vs[li * 8];
        *(float4*)(vv + 4) = *(float4*)&Vs[li * 8 + 4];
        float s0 = 0.f, s1 = 0.f;
#pragma unroll
        for (int d = 0; d < 8; d++) {
            s0 = fmaf(qa[d], kv[d], s0);
            s1 = fmaf(qc[d], kv[d], s1);
        }
        bool jv = (j >= 0) && (j < L_);
        bool ok0 = jv && (it != 64) && (it <= 128);
        bool ok1 = jv && (it != 65) && (it >= 1);
        float w0 = ok0 ? __expf(s0) : 0.f;
        float w1 = ok1 ? __expf(s1) : 0.f;
        l0 += w0; l1 += w1;
#pragma unroll
        for (int d = 0; d < 8; d++) {
            A0[d] = fmaf(w0, vv[d], A0[d]);
            A1[d] = fmaf(w1, vv[d], A1[d]);
        }
    }
    float i0 = 1.f / l0, i1 = 1.f / l1;
    int b = bh >> 4, h = bh & 15;
    int tb = b * L_ + q0;
#pragma unroll
    for (int d = 0; d < 8; d++) {               // col-major ctx
        g_ctx[(size_t)(h * 8 + d) * LDX + tb]     = A0[d] * i0;
        g_ctx[(size_t)(h * 8 + d) * LDX + tb + 1] = A1[d] * i1;
    }
}

// ---------------------------------------------------------------------------
extern "C" void kernel_launch(void* const* d_in, const int* in_sizes, int n_in,
                              void* d_out, int out_size, void* d_ws, size_t ws_size,
                              hipStream_t stream) {
    const float* x         = (const float*)d_in[0];
    const float* conv_w    = (const float*)d_in[1];
    const float* conv_b    = (const float*)d_in[2];
    const float* bn_g      = (const float*)d_in[3];
    const float* bn_b      = (const float*)d_in[4];
    const float* bn_rm     = (const float*)d_in[5];
    const float* bn_rv     = (const float*)d_in[6];
    const float* in_proj_w = (const float*)d_in[7];
    const float* in_proj_b = (const float*)d_in[8];
    const float* out_w     = (const float*)d_in[9];
    const float* out_b     = (const float*)d_in[10];
    const float* ff_w1     = (const float*)d_in[11];
    const float* ff_b1     = (const float*)d_in[12];
    const float* ff_w2     = (const float*)d_in[13];
    const float* ff_b2     = (const float*)d_in[14];
    const float* fc_w      = (const float*)d_in[15];
    const float* fc_b      = (const float*)d_in[16];

    // device-global symbol addresses (host-side)
    float *p_xT, *p_h, *p_ctx, *p_f1, *p_WconvT, *p_WqkvT, *p_Wf1T, *p_WfcT, *p_bf1, *p_bfc;
    hipGetSymbolAddress((void**)&p_xT,     HIP_SYMBOL(g_xT));
    hipGetSymbolAddress((void**)&p_h,      HIP_SYMBOL(g_h));
    hipGetSymbolAddress((void**)&p_ctx,    HIP_SYMBOL(g_ctx));
    hipGetSymbolAddress((void**)&p_f1,     HIP_SYMBOL(g_f1));
    hipGetSymbolAddress((void**)&p_WconvT, HIP_SYMBOL(g_WconvT));
    hipGetSymbolAddress((void**)&p_WqkvT,  HIP_SYMBOL(g_WqkvT));
    hipGetSymbolAddress((void**)&p_Wf1T,   HIP_SYMBOL(g_Wf1T));
    hipGetSymbolAddress((void**)&p_WfcT,   HIP_SYMBOL(g_WfcT));
    hipGetSymbolAddress((void**)&p_bf1,    HIP_SYMBOL(g_bf1));
    hipGetSymbolAddress((void**)&p_bfc,    HIP_SYMBOL(g_bfc));

    prep_fold<<<3432, 256, 0, stream>>>(x, conv_w, in_proj_w, out_w, out_b,
                                        ff_w1, ff_b1, ff_w2, ff_b2, fc_w, fc_b);

    // conv+relu+bn+pos: K=80
    gemm_kernel<80, 128, 2><<<dim3(128, 2), 256, 0, stream>>>(
        p_xT, p_WconvT, conv_b, bn_g, bn_b, bn_rm, bn_rv, p_h);

    // qkv: K=128, N=384 (6 col-blocks), scatter head-major
    gemm_kernel<128, 384, 3><<<dim3(128, 6), 256, 0, stream>>>(
        p_h, p_WqkvT, in_proj_b, nullptr, nullptr, nullptr, nullptr, nullptr);

    attn_kernel<<<dim3(64, 8), 128, 0, stream>>>();

    // fused out_proj+ff1: relu(ctx·M1^T + b1')
    gemm_kernel<128, 128, 1><<<dim3(128, 2), 256, 0, stream>>>(
        p_ctx, p_Wf1T, p_bf1, nullptr, nullptr, nullptr, nullptr, p_f1);

    // fused ff2+fc: f1·M2^T + b2' -> row-major output
    gemm_kernel<128, 128, 4><<<dim3(128, 2), 256, 0, stream>>>(
        p_f1, p_WfcT, p_bfc, nullptr, nullptr, nullptr, nullptr, (float*)d_out);
}

// Round 6
// 164.371 us; speedup vs baseline: 4.4474x; 1.0677x over previous
//
#include <hip/hip_runtime.h>
#include <hip/hip_bf16.h>
#include <math.h>

constexpr int B_ = 4, L_ = 2048, DIN = 80, D_ = 128, H_ = 16, DH = 8;
constexpr int T_ = B_ * L_;
constexpr int LDX = T_;              // col-major activations act[chan][token]
constexpr int BHL = B_ * H_ * L_;    // 131072 (bh, l) pairs

// ---- static device globals ----
__device__ float g_xT  [DIN * T_];          // [80][8192]
__device__ float g_posT[D_ * L_];           // [128][2048]
__device__ float g_h   [D_ * T_];           // col-major
__device__ float g_qkv [3 * D_ * T_];       // col-major [384][8192]
__device__ float g_ctx [D_ * T_];
__device__ float g_f1  [D_ * T_];
__device__ float g_pA  [2 * 8 * BHL];       // attn partial A  [half][d][bh*2048+l]
__device__ float g_pl  [2 * BHL];           // attn partial lsum
__device__ float g_WconvT[DIN * D_];        // [k][o]
__device__ float g_WqkvT [D_ * 3 * D_];     // [128][384]
__device__ float g_Wf1T  [D_ * D_];         // fused (W1*Wo)^T  [d][f]
__device__ float g_WfcT  [D_ * D_];         // fused (Wfc*W2)^T [f][o], o>=80 zero
__device__ float g_bf1   [D_];
__device__ float g_bfc   [D_];

// ---------------------------------------------------------------------------
// prep: xT LDS-tile transpose | fp32 posenc | weight transposes | folds
// grid 1000 x 256
// ---------------------------------------------------------------------------
__global__ __launch_bounds__(256) void prep_kernel(
        const float* __restrict__ x,
        const float* __restrict__ conv_w,
        const float* __restrict__ in_proj_w,
        const float* __restrict__ out_w,  const float* __restrict__ out_b,
        const float* __restrict__ ff_w1,  const float* __restrict__ ff_b1,
        const float* __restrict__ ff_w2,  const float* __restrict__ ff_b2,
        const float* __restrict__ fc_w,   const float* __restrict__ fc_b) {
    __shared__ float smem[80 * 65];
    int bid = blockIdx.x, tid = threadIdx.x;

    if (bid < 128) {                           // x [8192][80] -> xT [80][8192]
        int t0 = bid * 64;
        for (int i = tid; i < 64 * 80; i += 256) {
            int t = i / 80, k = i - t * 80;    // read coalesced (flat row-major)
            smem[k * 65 + t] = x[(size_t)(t0) * 80 + i];
        }
        __syncthreads();
        for (int i = tid; i < 80 * 64; i += 256) {
            int k = i >> 6, tt = i & 63;       // write coalesced per channel
            g_xT[(size_t)k * T_ + t0 + tt] = smem[k * 65 + tt];
        }
        return;
    }
    if (bid < 640) {                           // posenc fp32
        int idx = (bid - 128) * 256 + tid;     // [0, 131072)
        int l = idx >> 6, j = idx & 63;
        float inv = __expf((float)j * (-9.210340371976184f / 128.0f));
        float ang = (float)l * inv;
        g_posT[(2 * j) * L_ + l]     = sinf(ang);
        g_posT[(2 * j + 1) * L_ + l] = cosf(ang);
        return;
    }
    if (bid < 680) {                           // conv_w [128][80] -> [80][128]
        int e = (bid - 640) * 256 + tid;
        int o = e / 80, k = e - o * 80;
        g_WconvT[k * D_ + o] = conv_w[e];
        return;
    }
    if (bid < 872) {                           // in_proj_w [384][128] -> [128][384]
        int e = (bid - 680) * 256 + tid;
        int o = e >> 7, k = e & 127;
        g_WqkvT[k * (3 * D_) + o] = in_proj_w[e];
        return;
    }
    float* rowbuf = smem;                      // [2][128]
    float* red = smem + 256;                   // [256]
    if (bid < 936) {                           // fold1: M1=W1*Wo, b1'=W1*bo+b1
        int sub = tid >> 7, k = tid & 127;
        int f = (bid - 872) * 2 + sub;
        rowbuf[sub * 128 + k] = ff_w1[f * 128 + k];
        __syncthreads();
        float acc = 0.f;
#pragma unroll 8
        for (int o = 0; o < 128; o++)
            acc = fmaf(rowbuf[sub * 128 + o], out_w[o * 128 + k], acc);
        g_Wf1T[k * 128 + f] = acc;
        red[tid] = rowbuf[sub * 128 + k] * out_b[k];
        __syncthreads();
        for (int s = 64; s > 0; s >>= 1) {
            if (k < s) red[tid] += red[tid + s];
            __syncthreads();
        }
        if (k == 0) g_bf1[f] = red[sub * 128] + ff_b1[f];
        return;
    }
    {                                          // fold2: M2=Wfc*W2, b2'=Wfc*b2+bfc
        int sub = tid >> 7, k = tid & 127;
        int o = (bid - 936) * 2 + sub;
        rowbuf[sub * 128 + k] = (o < 80) ? fc_w[o * 128 + k] : 0.f;
        __syncthreads();
        float acc = 0.f;
#pragma unroll 8
        for (int d = 0; d < 128; d++)
            acc = fmaf(rowbuf[sub * 128 + d], ff_w2[d * 128 + k], acc);
        g_WfcT[k * 128 + o] = acc;
        red[tid] = rowbuf[sub * 128 + k] * ff_b2[k];
        __syncthreads();
        for (int s = 64; s > 0; s >>= 1) {
            if (k < s) red[tid] += red[tid + s];
            __syncthreads();
        }
        if (k == 0) g_bfc[o] = (o < 80) ? (red[sub * 128] + fc_b[o]) : 0.f;
        return;
    }
}

// ---------------------------------------------------------------------------
// GEMM: BM=64 tokens x BN cols, 256 threads as 16x16, TM=4 x TN=BN/16.
// Y[c][t] = epi( sum_k X[k][t]*Wt[k][c] + bias[c] )
// EPI: 0 none, 1 relu, 2 conv(relu+bn+pos), 4 fc row-major [t][80]
// ---------------------------------------------------------------------------
template <int K, int BK, int BN, int LDW, int EPI>
__global__ __launch_bounds__(256) void gemm_kernel(
        const float* __restrict__ X, const float* __restrict__ Wt,
        const float* __restrict__ bias,
        const float* __restrict__ bg, const float* __restrict__ bb,
        const float* __restrict__ brm, const float* __restrict__ brv,
        float* __restrict__ Y) {
    constexpr int TN = BN / 16;
    __shared__ float Xs[BK][64];
    __shared__ float Ws[BK][BN];
    int tid = threadIdx.x;
    int t0 = blockIdx.x * 64;
    int cb = blockIdx.y * BN;
    int tc = tid & 15, tr = tid >> 4;

    float acc[4][TN] = {};
    for (int kc = 0; kc < K; kc += BK) {
        for (int i = tid; i < BK * 16; i += 256) {        // X tile
            int k = i >> 4, f = i & 15;
            *(float4*)&Xs[k][f * 4] =
                *(const float4*)&X[(size_t)(kc + k) * LDX + t0 + f * 4];
        }
        for (int i = tid; i < BK * (BN / 4); i += 256) {  // W tile
            int k = i / (BN / 4), f = i - k * (BN / 4);
            *(float4*)&Ws[k][f * 4] =
                *(const float4*)&Wt[(size_t)(kc + k) * LDW + cb + f * 4];
        }
        __syncthreads();
#pragma unroll 4
        for (int k = 0; k < BK; ++k) {
            float4 a = *(float4*)&Xs[k][tr * 4];
            float av[4] = {a.x, a.y, a.z, a.w};
            float wv[TN];
#pragma unroll
            for (int jj = 0; jj < TN; jj++) wv[jj] = Ws[k][tc * TN + jj];
#pragma unroll
            for (int i = 0; i < 4; i++)
#pragma unroll
                for (int jj = 0; jj < TN; jj++)
                    acc[i][jj] = fmaf(av[i], wv[jj], acc[i][jj]);
        }
        __syncthreads();
    }

    if (EPI == 4) {                            // row-major [t][80]
#pragma unroll
        for (int jj = 0; jj < TN; jj++) {
            int c = cb + tc * TN + jj;
            if (c < 80) {
                float bv = bias[c];
#pragma unroll
                for (int i = 0; i < 4; i++) {
                    int t = t0 + tr * 4 + i;
                    Y[(size_t)t * 80 + c] = acc[i][jj] + bv;
                }
            }
        }
        return;
    }
#pragma unroll
    for (int jj = 0; jj < TN; jj++) {
        int c = cb + tc * TN + jj;
        float bv = bias[c];
        float vs[4];
#pragma unroll
        for (int i = 0; i < 4; i++) {
            float v = acc[i][jj] + bv;
            if (EPI == 1) v = fmaxf(v, 0.0f);
            if (EPI == 2) {
                v = fmaxf(v, 0.0f);
                v = (v - brm[c]) * (bg[c] * rsqrtf(brv[c] + 1e-5f)) + bb[c];
                v += g_posT[c * L_ + ((t0 & 2047) + tr * 4 + i)];
            }
            vs[i] = v;
        }
        *(float4*)&Y[(size_t)c * LDX + t0 + tr * 4] = *(float4*)vs;
    }
}

// ---------------------------------------------------------------------------
// Attention halves. Block = (bh, 256-q tile, half). 128 thr, 2 adjacent q each.
// half 0: keys j in [q-64, q) ; half 1: keys j in (q, q+64]. Diagonal excluded
// structurally. K/V staged in parity-split float4 arrays: inner ds_read_b128
// is consecutive-lane -> conflict-free.
// ---------------------------------------------------------------------------
__global__ __launch_bounds__(128) void attn_kernel() {
    __shared__ float4 SK[2][2][160];
    __shared__ float4 SV[2][2][160];
    int bh = blockIdx.x, tile = blockIdx.y, hf = blockIdx.z;
    int b = bh >> 4, h = bh & 15;
    int qb = tile * 256;
    int tid = threadIdx.x;
    int jbase = hf ? (qb + 1) : (qb - 64);
    int tb = b * L_;

    for (int c16 = 0; c16 < 16; c16++) {       // stage 16 channels x 319 slots
        int d = (c16 < 8) ? c16 : (c16 - 8);
        int ch = ((c16 < 8) ? 128 : 256) + h * 8 + d;
        const float* src = g_qkv + (size_t)ch * LDX + tb;
        for (int s = tid; s < 319; s += 128) {
            int j = jbase + s;
            float v = ((unsigned)j < (unsigned)L_) ? src[j] : 0.f;
            float4* arr = (c16 < 8) ? &SK[s & 1][d >> 2][s >> 1]
                                    : &SV[s & 1][d >> 2][s >> 1];
            ((float*)arr)[d & 3] = v;
        }
    }
    __syncthreads();

    const float sc = 0.35355339059327373f;     // 1/sqrt(8)
    int q0 = qb + 2 * tid;
    float qa[8], qc[8];
    {
        const float* qsrc = g_qkv + tb;
#pragma unroll
        for (int d = 0; d < 8; d++) {
            qa[d] = qsrc[(size_t)(h * 8 + d) * LDX + q0] * sc;
            qc[d] = qsrc[(size_t)(h * 8 + d) * LDX + q0 + 1] * sc;
        }
    }

    float l0 = 0.f, l1 = 0.f;
    float A0[8] = {}, A1[8] = {};
    int j00 = jbase + 2 * tid;

    auto step = [&](int it, bool m0, bool m1) {
        int p = it & 1, idx = tid + (it >> 1);
        float4 ka = SK[p][0][idx], kb = SK[p][1][idx];
        float kv[8] = {ka.x, ka.y, ka.z, ka.w, kb.x, kb.y, kb.z, kb.w};
        float s0 = 0.f, s1 = 0.f;
#pragma unroll
        for (int d = 0; d < 8; d++) {
            s0 = fmaf(qa[d], kv[d], s0);
            s1 = fmaf(qc[d], kv[d], s1);
        }
        bool jv = (unsigned)(j00 + it) < (unsigned)L_;
        float w0 = (m0 && jv) ? __expf(s0) : 0.f;
        float w1 = (m1 && jv) ? __expf(s1) : 0.f;
        l0 += w0; l1 += w1;
        float4 va = SV[p][0][idx], vb = SV[p][1][idx];
        float vv[8] = {va.x, va.y, va.z, va.w, vb.x, vb.y, vb.z, vb.w};
#pragma unroll
        for (int d = 0; d < 8; d++) {
            A0[d] = fmaf(w0, vv[d], A0[d]);
            A1[d] = fmaf(w1, vv[d], A1[d]);
        }
    };

    step(0, true, false);                      // it=0: q1 inactive
#pragma unroll 2
    for (int it = 1; it <= 63; it++) step(it, true, true);
    step(64, false, true);                     // it=64: q0 inactive

    int base = bh * L_ + q0;
#pragma unroll
    for (int d = 0; d < 8; d++) {
        g_pA[(hf * 8 + d) * BHL + base]     = A0[d];
        g_pA[(hf * 8 + d) * BHL + base + 1] = A1[d];
    }
    g_pl[hf * BHL + base]     = l0;
    g_pl[hf * BHL + base + 1] = l1;
}

// combine halves -> ctx col-major
__global__ __launch_bounds__(256) void combine_kernel() {
    int gq = blockIdx.x * 256 + threadIdx.x;   // [0, 131072)
    int bh = gq >> 11, l = gq & 2047;
    int b = bh >> 4, h = bh & 15;
    float ls = g_pl[gq] + g_pl[BHL + gq];
    float inv = 1.f / ls;
#pragma unroll
    for (int d = 0; d < 8; d++) {
        float v = (g_pA[d * BHL + gq] + g_pA[(8 + d) * BHL + gq]) * inv;
        g_ctx[(size_t)(h * 8 + d) * LDX + b * L_ + l] = v;
    }
}

// ---------------------------------------------------------------------------
extern "C" void kernel_launch(void* const* d_in, const int* in_sizes, int n_in,
                              void* d_out, int out_size, void* d_ws, size_t ws_size,
                              hipStream_t stream) {
    const float* x         = (const float*)d_in[0];
    const float* conv_w    = (const float*)d_in[1];
    const float* conv_b    = (const float*)d_in[2];
    const float* bn_g      = (const float*)d_in[3];
    const float* bn_b      = (const float*)d_in[4];
    const float* bn_rm     = (const float*)d_in[5];
    const float* bn_rv     = (const float*)d_in[6];
    const float* in_proj_w = (const float*)d_in[7];
    const float* in_proj_b = (const float*)d_in[8];
    const float* out_w     = (const float*)d_in[9];
    const float* out_b     = (const float*)d_in[10];
    const float* ff_w1     = (const float*)d_in[11];
    const float* ff_b1     = (const float*)d_in[12];
    const float* ff_w2     = (const float*)d_in[13];
    const float* ff_b2     = (const float*)d_in[14];
    const float* fc_w      = (const float*)d_in[15];
    const float* fc_b      = (const float*)d_in[16];

    float *p_xT, *p_h, *p_qkv, *p_ctx, *p_f1;
    float *p_WconvT, *p_WqkvT, *p_Wf1T, *p_WfcT, *p_bf1, *p_bfc;
    hipGetSymbolAddress((void**)&p_xT,     HIP_SYMBOL(g_xT));
    hipGetSymbolAddress((void**)&p_h,      HIP_SYMBOL(g_h));
    hipGetSymbolAddress((void**)&p_qkv,    HIP_SYMBOL(g_qkv));
    hipGetSymbolAddress((void**)&p_ctx,    HIP_SYMBOL(g_ctx));
    hipGetSymbolAddress((void**)&p_f1,     HIP_SYMBOL(g_f1));
    hipGetSymbolAddress((void**)&p_WconvT, HIP_SYMBOL(g_WconvT));
    hipGetSymbolAddress((void**)&p_WqkvT,  HIP_SYMBOL(g_WqkvT));
    hipGetSymbolAddress((void**)&p_Wf1T,   HIP_SYMBOL(g_Wf1T));
    hipGetSymbolAddress((void**)&p_WfcT,   HIP_SYMBOL(g_WfcT));
    hipGetSymbolAddress((void**)&p_bf1,    HIP_SYMBOL(g_bf1));
    hipGetSymbolAddress((void**)&p_bfc,    HIP_SYMBOL(g_bfc));

    prep_kernel<<<1000, 256, 0, stream>>>(x, conv_w, in_proj_w, out_w, out_b,
                                          ff_w1, ff_b1, ff_w2, ff_b2, fc_w, fc_b);

    // conv+relu+bn+pos: K=80 single chunk, BN=32, grid 512
    gemm_kernel<80, 80, 32, 128, 2><<<dim3(128, 4), 256, 0, stream>>>(
        p_xT, p_WconvT, conv_b, bn_g, bn_b, bn_rm, bn_rv, p_h);

    // qkv: K=128 BK=64, BN=64, col-major out, grid 768
    gemm_kernel<128, 64, 64, 384, 0><<<dim3(128, 6), 256, 0, stream>>>(
        p_h, p_WqkvT, in_proj_b, nullptr, nullptr, nullptr, nullptr, p_qkv);

    attn_kernel<<<dim3(64, 8, 2), 128, 0, stream>>>();
    combine_kernel<<<512, 256, 0, stream>>>();

    // fused out_proj+ff1: relu(ctx*M1^T + b1'), grid 512
    gemm_kernel<128, 128, 32, 128, 1><<<dim3(128, 4), 256, 0, stream>>>(
        p_ctx, p_Wf1T, p_bf1, nullptr, nullptr, nullptr, nullptr, p_f1);

    // fused ff2+fc -> row-major [t][80], grid 384 (col tiles 0..95 cover N=80)
    gemm_kernel<128, 128, 32, 128, 4><<<dim3(128, 3), 256, 0, stream>>>(
        p_f1, p_WfcT, p_bfc, nullptr, nullptr, nullptr, nullptr, (float*)d_out);
}